// Round 7
// baseline (495.041 us; speedup 1.0000x reference)
//
#include <hip/hip_runtime.h>
#include <hip/hip_bf16.h>

#define NB 60000
#define NP 2000
#define NC 4000
#define EM_N 150000
#define EP_N 300000
#define EI_N 150000
#define POOL_N (EM_N + EP_N + EI_N)
#define SEG_TOT (NB + NB + NC)                        // 124000 segment counters
#define SCAN_BLK 1024
#define NPART ((SEG_TOT + SCAN_BLK - 1) / SCAN_BLK)   // 122

typedef __hip_bfloat16 bf16;
typedef __attribute__((ext_vector_type(8))) short s8v;   // 8 bf16 raw bits (4 VGPRs)
typedef __attribute__((ext_vector_type(4))) float f4v;

__device__ __forceinline__ float toF(float x) { return x; }
__device__ __forceinline__ float toF(bf16 x) { return __bfloat162float(x); }
__device__ __forceinline__ void stC(float* C, size_t idx, float v) { C[idx] = v; }
__device__ __forceinline__ void stC(bf16* C, size_t idx, float v) { C[idx] = __float2bfloat16(v); }
__device__ __forceinline__ short f2bs(float f) {
    bf16 h = __float2bfloat16(f);
    return __builtin_bit_cast(short, h);
}
__device__ __forceinline__ float bsToF(short s) {
    return __builtin_bit_cast(float, ((unsigned)(unsigned short)s) << 16);
}

// ---------------- generic VALU GEMM (small M): C[M,128] = A[M,128] @ W[128,128] ----------------
template<typename AT, typename CT, bool BIAS>
__global__ void gemm128_kernel(const AT* __restrict__ A, const float* __restrict__ W,
                               const float* __restrict__ bias, CT* __restrict__ C, int M) {
    __shared__ float Al[16 * 128];
    const int tid = threadIdx.x;
    const int row0 = blockIdx.x * 16;
    for (int i = tid; i < 16 * 128; i += 256) {
        int r = row0 + (i >> 7);
        Al[i] = (r < M) ? toF(A[(size_t)r * 128 + (i & 127)]) : 0.f;
    }
    __syncthreads();
    const int col = tid & 127, rg = tid >> 7;
    float acc[8];
#pragma unroll
    for (int i = 0; i < 8; i++) acc[i] = 0.f;
    for (int k = 0; k < 128; k++) {
        float w = W[k * 128 + col];
#pragma unroll
        for (int i = 0; i < 8; i++) acc[i] += Al[(rg * 8 + i) * 128 + k] * w;
    }
    float bv = 0.f;
    if constexpr (BIAS) bv = bias[col];
#pragma unroll
    for (int i = 0; i < 8; i++) {
        int r = row0 + rg * 8 + i;
        if (r < M) stC(C, (size_t)r * 128 + col, acc[i] + bv);
    }
}

// ---------------- weight prep: Wt[w][n][k] = W_w[k][n] as bf16 bits ----------------
__global__ void wt_prep_kernel(const float* __restrict__ W0, const float* __restrict__ W1,
                               const float* __restrict__ W2, const float* __restrict__ W3,
                               const float* __restrict__ W4, ushort* __restrict__ Wt) {
    int t = blockIdx.x * 256 + threadIdx.x;
    if (t >= 5 * 16384) return;
    int w = t >> 14, r = t & 16383, k = r >> 7, n = r & 127;
    const float* W = (w == 0) ? W0 : (w == 1) ? W1 : (w == 2) ? W2 : (w == 3) ? W3 : W4;
    Wt[w * 16384 + n * 128 + k] = (ushort)f2bs(W[k * 128 + n]);
}

// ---------------- MFMA fused 5-matrix GEMM on x_ball ----------------
__global__ __launch_bounds__(256) void gemm5_mfma_kernel(
    const float* __restrict__ A, const ushort* __restrict__ Wt,
    const float* __restrict__ bq, const float* __restrict__ bk,
    const float* __restrict__ bv_, const float* __restrict__ bskip,
    bf16* __restrict__ xrB, bf16* __restrict__ qB, bf16* __restrict__ kvB,
    bf16* __restrict__ skipB) {
    const int lane = threadIdx.x & 63;
    const int wv = threadIdx.x >> 6;
    const int quad = lane >> 4, l16 = lane & 15;
    const int mbase = blockIdx.x * 128 + wv * 32;

    s8v a[2][4];
#pragma unroll
    for (int mt = 0; mt < 2; mt++) {
        int row = mbase + mt * 16 + l16;
        if (row >= NB) row = NB - 1;
        const float* ap = A + (size_t)row * 128 + quad * 8;
#pragma unroll
        for (int kt = 0; kt < 4; kt++) {
            const float4* p = (const float4*)(ap + kt * 32);
            float4 u = p[0], v = p[1];
            s8v f;
            f[0] = f2bs(u.x); f[1] = f2bs(u.y); f[2] = f2bs(u.z); f[3] = f2bs(u.w);
            f[4] = f2bs(v.x); f[5] = f2bs(v.y); f[6] = f2bs(v.z); f[7] = f2bs(v.w);
            a[mt][kt] = f;
        }
    }

#pragma unroll
    for (int w = 0; w < 5; w++) {
        const ushort* wt = Wt + w * 16384;
        bf16* op; const float* bp; int stride;
        if (w == 0)      { op = xrB;       bp = nullptr; stride = 128; }
        else if (w == 1) { op = qB;        bp = bq;      stride = 128; }
        else if (w == 2) { op = kvB;       bp = bk;      stride = 256; }
        else if (w == 3) { op = kvB + 128; bp = bv_;     stride = 256; }
        else             { op = skipB;     bp = bskip;   stride = 128; }
#pragma unroll
        for (int nt = 0; nt < 8; nt++) {
            int col = nt * 16 + l16;
            s8v b[4];
#pragma unroll
            for (int kt = 0; kt < 4; kt++)
                b[kt] = *(const s8v*)(wt + col * 128 + kt * 32 + quad * 8);
            float bval = bp ? bp[col] : 0.f;
#pragma unroll
            for (int mt = 0; mt < 2; mt++) {
                f4v acc = {0.f, 0.f, 0.f, 0.f};
#pragma unroll
                for (int kt = 0; kt < 4; kt++)
                    acc = __builtin_amdgcn_mfma_f32_16x16x32_bf16(a[mt][kt], b[kt], acc, 0, 0, 0);
#pragma unroll
                for (int r = 0; r < 4; r++) {
                    int row = mbase + mt * 16 + quad * 4 + r;
                    if (row < NB)
                        op[(size_t)row * stride + col] = __float2bfloat16(acc[r] + bval);
                }
            }
        }
    }
}

// ---------------- CSR build ----------------
__global__ void hist_all_kernel(const int* __restrict__ em, const int* __restrict__ ep,
                                const int* __restrict__ ei, int* __restrict__ counts) {
    int t = blockIdx.x * 256 + threadIdx.x;
    if (t < EM_N) atomicAdd(&counts[em[EM_N + t]], 1);
    else if (t < EM_N + EP_N) atomicAdd(&counts[NB + ep[EP_N + (t - EM_N)]], 1);
    else if (t < POOL_N) atomicAdd(&counts[2 * NB + ei[EI_N + (t - EM_N - EP_N)]], 1);
}

__global__ void scan1_kernel(const int* __restrict__ counts, int* __restrict__ offsets,
                             int* __restrict__ partials) {
    __shared__ int sd[256];
    int b = blockIdx.x, tid = threadIdx.x;
    int base = b * SCAN_BLK + tid * 4;
    int v[4]; int ts = 0;
#pragma unroll
    for (int j = 0; j < 4; j++) { int idx = base + j; v[j] = (idx < SEG_TOT) ? counts[idx] : 0; ts += v[j]; }
    sd[tid] = ts;
    for (int off = 1; off < 256; off <<= 1) {
        __syncthreads(); int t = (tid >= off) ? sd[tid - off] : 0;
        __syncthreads(); sd[tid] += t;
    }
    int run = sd[tid] - ts;
#pragma unroll
    for (int j = 0; j < 4; j++) { int idx = base + j; if (idx < SEG_TOT) offsets[idx] = run; run += v[j]; }
    if (tid == 255) partials[b] = sd[255];
}

__global__ void scan2_kernel(int* __restrict__ partials) {
    __shared__ int sd[256];
    int tid = threadIdx.x;
    int v = (tid < NPART) ? partials[tid] : 0;
    sd[tid] = v;
    for (int off = 1; off < 256; off <<= 1) {
        __syncthreads(); int t = (tid >= off) ? sd[tid - off] : 0;
        __syncthreads(); sd[tid] += t;
    }
    if (tid < NPART) partials[tid] = sd[tid] - v;
}

__global__ void scan3_kernel(int* __restrict__ offsets, const int* __restrict__ partials,
                             int* __restrict__ cursors) {
    int t = blockIdx.x * 256 + threadIdx.x;
    if (t >= SEG_TOT) return;
    int o = offsets[t] + partials[t >> 10];
    offsets[t] = o;
    cursors[t] = o;
}

__global__ void fill_all_kernel(const int* __restrict__ em, const int* __restrict__ ep,
                                const int* __restrict__ ei, const float* __restrict__ ea_p,
                                int* __restrict__ cursors, int* __restrict__ psrc,
                                float* __restrict__ pea) {
    int t = blockIdx.x * 256 + threadIdx.x;
    int seg, s; float ea = 0.f;
    if (t < EM_N) { s = em[t]; seg = em[EM_N + t]; }
    else if (t < EM_N + EP_N) { int e = t - EM_N; s = ep[e]; seg = NB + ep[EP_N + e]; ea = ea_p[e]; }
    else if (t < POOL_N) { int e = t - EM_N - EP_N; s = ei[e]; seg = 2 * NB + ei[EI_N + e]; }
    else return;
    int pos = atomicAdd(&cursors[seg], 1);
    psrc[pos] = s; pea[pos] = ea;
}

// ---------------- fused ball node kernel: pair-parallel logits + gather agg + LN ----------------
// One wave per ball node. Edges in chunks of 16: phase A = lane per (edge,head) pair
// computes exp-logit; phase B = element-ownership aggregation via bpermute/readlane.
__global__ __launch_bounds__(256) void ball_node_kernel(
    const ushort* __restrict__ xl, const ushort* __restrict__ xr, const ushort* __restrict__ qB,
    const ushort* __restrict__ kv, const ushort* __restrict__ skip,
    const float* __restrict__ x_ball, const float* __restrict__ g_att, const float* __restrict__ g_b,
    const float* __restrict__ We,
    const int* __restrict__ offsets, const int* __restrict__ counts,
    const int* __restrict__ psrc, const float* __restrict__ pea,
    const float* __restrict__ ln_g, const float* __restrict__ ln_b, float* __restrict__ out) {
    const int wv = threadIdx.x >> 6, l = threadIdx.x & 63;
    const int d = blockIdx.x * 4 + wv;
    if (d >= NB) return;
    const int hl = l >> 5;           // head-slot offset for elem l (head hl) / l+64 (head 2+hl)
    const int e4 = l >> 2, hh = l & 3;
    const size_t rowD = (size_t)d * 128;

    // ======== GATv2 (player -> ball) ========
    int beg = offsets[d], cnt = counts[d];
    float n0 = 0.f, n1 = 0.f, de0 = 0.f, de1 = 0.f;
    for (int base = 0; base < cnt; base += 16) {
        int c = cnt - base; if (c > 16) c = 16;
        float pe = 0.f; int ssrc = 0;
        if (e4 < c) {
            int pos = beg + base + e4;
            int s = psrc[pos]; ssrc = s;
            const ushort* lp = xl + (size_t)s * 128 + hh * 32;
            const ushort* rp = xr + rowD + hh * 32;
            const float* ap = g_att + hh * 32;
            float acc = 0.f;
#pragma unroll
            for (int kt = 0; kt < 4; kt++) {
                s8v lv = *(const s8v*)(lp + kt * 8);
                s8v rv = *(const s8v*)(rp + kt * 8);
#pragma unroll
                for (int j = 0; j < 8; j++) {
                    float u = bsToF(lv[j]) + bsToF(rv[j]);
                    u = u > 0.f ? u : 0.2f * u;
                    acc += u * ap[kt * 8 + j];
                }
            }
            pe = __expf(acc);
        }
        for (int j = 0; j < c; j++) {
            int s = __shfl(ssrc, j * 4);             // readlane (uniform idx)
            float p0 = __shfl(pe, j * 4 + hl);       // bpermute
            float p1 = __shfl(pe, j * 4 + 2 + hl);   // bpermute
            const ushort* xp = xl + (size_t)s * 128;
            n0 += p0 * bsToF(xp[l]);
            n1 += p1 * bsToF(xp[l + 64]);
            de0 += p0; de1 += p1;
        }
    }
    float gat0 = n0 / (de0 + 1e-16f), gat1 = n1 / (de1 + 1e-16f);

    // ======== TransformerConv (ball -> ball) ========
    beg = offsets[NB + d]; cnt = counts[NB + d];
    float sv0 = 0.f, sv1 = 0.f, sp0 = 0.f, sp1 = 0.f;
    de0 = de1 = 0.f;
    for (int base = 0; base < cnt; base += 16) {
        int c = cnt - base; if (c > 16) c = 16;
        float pe = 0.f, eaR = 0.f; int ssrc = 0;
        if (e4 < c) {
            int pos = beg + base + e4;
            int s = psrc[pos]; ssrc = s;
            float ea = pea[pos]; eaR = ea;
            const ushort* kp = kv + (size_t)s * 256 + hh * 32;
            const ushort* qp = qB + rowD + hh * 32;
            const float* wp = We + hh * 32;
            float acc = 0.f;
#pragma unroll
            for (int kt = 0; kt < 4; kt++) {
                s8v kf = *(const s8v*)(kp + kt * 8);
                s8v qf = *(const s8v*)(qp + kt * 8);
#pragma unroll
                for (int j = 0; j < 8; j++)
                    acc += bsToF(qf[j]) * (bsToF(kf[j]) + ea * wp[kt * 8 + j]);
            }
            pe = __expf(acc * 0.17677669529663687f);   // 1/sqrt(32)
        }
        for (int j = 0; j < c; j++) {
            int s = __shfl(ssrc, j * 4);
            float ea = __shfl(eaR, j * 4);
            float p0 = __shfl(pe, j * 4 + hl);
            float p1 = __shfl(pe, j * 4 + 2 + hl);
            const ushort* vp = kv + (size_t)s * 256 + 128;
            sv0 += p0 * bsToF(vp[l]);
            sv1 += p1 * bsToF(vp[l + 64]);
            sp0 += p0 * ea; sp1 += p1 * ea;
            de0 += p0; de1 += p1;
        }
    }
    float tr0 = (sv0 + sp0 * We[l]) / (de0 + 1e-16f);
    float tr1 = (sv1 + sp1 * We[l + 64]) / (de1 + 1e-16f);

    // ======== skip + residual + LayerNorm ========
    float val0 = bsToF(((const short*)skip)[rowD + l]) + gat0 + tr0 + x_ball[rowD + l] + g_b[l];
    float val1 = bsToF(((const short*)skip)[rowD + l + 64]) + gat1 + tr1 + x_ball[rowD + l + 64] + g_b[l + 64];
    float s = val0 + val1;
#pragma unroll
    for (int m = 1; m <= 32; m <<= 1) s += __shfl_xor(s, m);
    float mu = s * (1.f / 128.f);
    float d0 = val0 - mu, d1 = val1 - mu;
    float qv = d0 * d0 + d1 * d1;
#pragma unroll
    for (int m = 1; m <= 32; m <<= 1) qv += __shfl_xor(qv, m);
    float inv = rsqrtf(qv * (1.f / 128.f) + 1e-5f);
    out[rowD + l] = d0 * inv * ln_g[l] + ln_b[l];
    out[rowD + l + 64] = d1 * inv * ln_g[l + 64] + ln_b[l + 64];
}

// ---------------- SAGE gather, 4-way edge split per node ----------------
__global__ void sage_gather4_kernel(const float* __restrict__ x_ball,
                                    const int* __restrict__ offsets, const int* __restrict__ counts,
                                    const int* __restrict__ psrc, float* __restrict__ summ) {
    __shared__ float part[4][128];
    int c = blockIdx.x;
    int w = threadIdx.x >> 6, l = threadIdx.x & 63;
    int beg = offsets[2 * NB + c], cnt = counts[2 * NB + c];
    float s0 = 0.f, s1 = 0.f;
    for (int j = w; j < cnt; j += 4) {
        int s = psrc[beg + j];
        size_t rs = (size_t)s * 128;
        s0 += x_ball[rs + l];
        s1 += x_ball[rs + l + 64];
    }
    part[w][l] = s0; part[w][l + 64] = s1;
    __syncthreads();
    if (w == 0) {
        float m = fmaxf((float)cnt, 1.f);
        size_t rowC = (size_t)c * 128;
        summ[rowC + l] = (part[0][l] + part[1][l] + part[2][l] + part[3][l]) / m;
        summ[rowC + l + 64] = (part[0][l + 64] + part[1][l + 64] + part[2][l + 64] + part[3][l + 64]) / m;
    }
}

// ---------------- fused ctx: xc@Wr + summ@Wl + bl + residual + LN ----------------
__global__ void ctx_fused_kernel(const float* __restrict__ xc, const float* __restrict__ summ,
                                 const float* __restrict__ Wr, const float* __restrict__ Wl,
                                 const float* __restrict__ bl,
                                 const float* __restrict__ g, const float* __restrict__ b,
                                 float* __restrict__ out) {
    __shared__ float A0[16 * 128];
    __shared__ float A1[16 * 128];
    __shared__ float CB[16 * 128];
    const int tid = threadIdx.x;
    const int row0 = blockIdx.x * 16;
    for (int i = tid; i < 16 * 128; i += 256) {
        int r = row0 + (i >> 7);
        A0[i] = (r < NC) ? xc[(size_t)r * 128 + (i & 127)] : 0.f;
        A1[i] = (r < NC) ? summ[(size_t)r * 128 + (i & 127)] : 0.f;
    }
    __syncthreads();
    const int col = tid & 127, rg = tid >> 7;
    float acc[8];
#pragma unroll
    for (int i = 0; i < 8; i++) acc[i] = 0.f;
    for (int k = 0; k < 128; k++) {
        float w0 = Wr[k * 128 + col], w1 = Wl[k * 128 + col];
#pragma unroll
        for (int i = 0; i < 8; i++)
            acc[i] += A0[(rg * 8 + i) * 128 + k] * w0 + A1[(rg * 8 + i) * 128 + k] * w1;
    }
    float bv = bl[col];
#pragma unroll
    for (int i = 0; i < 8; i++)
        CB[(rg * 8 + i) * 128 + col] = acc[i] + bv + A0[(rg * 8 + i) * 128 + col];  // + residual
    __syncthreads();
    const int wv = tid >> 6, l = tid & 63;
    for (int r = 0; r < 4; r++) {
        int lr = wv * 4 + r, row = row0 + lr;
        if (row >= NC) break;
        float v0 = CB[lr * 128 + l], v1 = CB[lr * 128 + l + 64];
        float s = v0 + v1;
#pragma unroll
        for (int m = 1; m <= 32; m <<= 1) s += __shfl_xor(s, m);
        float mu = s * (1.f / 128.f);
        float d0 = v0 - mu, d1 = v1 - mu;
        float qv = d0 * d0 + d1 * d1;
#pragma unroll
        for (int m = 1; m <= 32; m <<= 1) qv += __shfl_xor(qv, m);
        float inv = rsqrtf(qv * (1.f / 128.f) + 1e-5f);
        out[(size_t)row * 128 + l] = d0 * inv * g[l] + b[l];
        out[(size_t)row * 128 + l + 64] = d1 * inv * g[l + 64] + b[l + 64];
    }
}

__global__ void copy_player_kernel(const float* __restrict__ xp, float* __restrict__ out) {
    int t = blockIdx.x * 256 + threadIdx.x;
    if (t >= NP * 128) return;
    out[t] = xp[t];
}

extern "C" void kernel_launch(void* const* d_in, const int* in_sizes, int n_in,
                              void* d_out, int out_size, void* d_ws, size_t ws_size,
                              hipStream_t stream) {
    const float* x_ball = (const float*)d_in[0];
    const float* x_player = (const float*)d_in[1];
    const float* x_context = (const float*)d_in[2];
    const int* em = (const int*)d_in[3];
    const int* ep = (const int*)d_in[4];
    const int* ei = (const int*)d_in[5];
    const float* ea_p = (const float*)d_in[6];
    const float* g_Wl = (const float*)d_in[7];
    const float* g_Wr = (const float*)d_in[8];
    const float* g_att = (const float*)d_in[9];
    const float* g_b = (const float*)d_in[10];
    const float* t_Wq = (const float*)d_in[11];
    const float* t_bq = (const float*)d_in[12];
    const float* t_Wk = (const float*)d_in[13];
    const float* t_bk = (const float*)d_in[14];
    const float* t_Wv = (const float*)d_in[15];
    const float* t_bv = (const float*)d_in[16];
    const float* t_We = (const float*)d_in[17];
    const float* t_Wskip = (const float*)d_in[18];
    const float* t_bskip = (const float*)d_in[19];
    const float* s_Wl = (const float*)d_in[20];
    const float* s_bl = (const float*)d_in[21];
    const float* s_Wr = (const float*)d_in[22];
    const float* ln_ball_g = (const float*)d_in[23];
    const float* ln_ball_b = (const float*)d_in[24];
    const float* ln_ctx_g = (const float*)d_in[25];
    const float* ln_ctx_b = (const float*)d_in[26];
    float* out = (float*)d_out;

    // ---- workspace (~90 MB) ----
    float* ws = (float*)d_ws;
    size_t o = 0;
    float* summ = ws + o;     o += (size_t)NC * 128;
    float* pea = ws + o;      o += POOL_N;
    int* counts = (int*)(ws + o);   o += SEG_TOT;
    int* offsets = (int*)(ws + o);  o += SEG_TOT;
    int* cursors = (int*)(ws + o);  o += SEG_TOT;
    int* partials = (int*)(ws + o); o += 128;
    int* psrc = (int*)(ws + o);     o += POOL_N;
    ushort* Wt = (ushort*)(ws + o); o += (5 * 16384) / 2;
    bf16* bws = (bf16*)(ws + o);
    size_t ob = 0;
    bf16* xl = bws + ob;    ob += (size_t)NP * 128;
    bf16* xrB = bws + ob;   ob += (size_t)NB * 128;
    bf16* qB = bws + ob;    ob += (size_t)NB * 128;
    bf16* kvB = bws + ob;   ob += (size_t)NB * 256;   // k|v interleaved per node
    bf16* skipB = bws + ob; ob += (size_t)NB * 128;

    dim3 blk(256);
    // ---- CSR build ----
    hipMemsetAsync(counts, 0, SEG_TOT * sizeof(int), stream);
    hist_all_kernel<<<(POOL_N + 255) / 256, blk, 0, stream>>>(em, ep, ei, counts);
    scan1_kernel<<<NPART, blk, 0, stream>>>(counts, offsets, partials);
    scan2_kernel<<<1, blk, 0, stream>>>(partials);
    scan3_kernel<<<(SEG_TOT + 255) / 256, blk, 0, stream>>>(offsets, partials, cursors);
    fill_all_kernel<<<(POOL_N + 255) / 256, blk, 0, stream>>>(em, ep, ei, ea_p, cursors, psrc, pea);

    // ---- dense projections ----
    wt_prep_kernel<<<(5 * 16384 + 255) / 256, blk, 0, stream>>>(g_Wr, t_Wq, t_Wk, t_Wv, t_Wskip, Wt);
    gemm128_kernel<float, bf16, false><<<(NP + 15) / 16, blk, 0, stream>>>(x_player, g_Wl, nullptr, xl, NP);
    gemm5_mfma_kernel<<<(NB + 127) / 128, blk, 0, stream>>>(x_ball, Wt, t_bq, t_bk, t_bv, t_bskip,
                                                            xrB, qB, kvB, skipB);

    // ---- fused ball pipeline (logits + softmax + agg + skip + residual + LN) ----
    ball_node_kernel<<<(NB + 3) / 4, blk, 0, stream>>>(
        (const ushort*)xl, (const ushort*)xrB, (const ushort*)qB, (const ushort*)kvB,
        (const ushort*)skipB, x_ball, g_att, g_b, t_We,
        offsets, counts, psrc, pea, ln_ball_g, ln_ball_b, out);

    // ---- SAGE -> ctx (fused GEMM+residual+LN) ----
    sage_gather4_kernel<<<NC, blk, 0, stream>>>(x_ball, offsets, counts, psrc, summ);
    ctx_fused_kernel<<<(NC + 15) / 16, blk, 0, stream>>>(x_context, summ, s_Wr, s_Wl, s_bl,
                                                         ln_ctx_g, ln_ctx_b, out + (size_t)NB * 128);
    copy_player_kernel<<<(NP * 128 + 255) / 256, blk, 0, stream>>>(x_player,
                                                                   out + (size_t)(NB + NC) * 128);
}

// Round 8
// 378.925 us; speedup vs baseline: 1.3064x; 1.3064x over previous
//
#include <hip/hip_runtime.h>
#include <hip/hip_bf16.h>

#define NB 60000
#define NP 2000
#define NC 4000
#define EM_N 150000
#define EP_N 300000
#define EI_N 150000
#define POOL_N (EM_N + EP_N + EI_N)
#define SEG_TOT (NB + NB + NC)
#define SCAN_BLK 1024
#define NPART ((SEG_TOT + SCAN_BLK - 1) / SCAN_BLK)   // 122

typedef __hip_bfloat16 bf16;
typedef unsigned int u32;
typedef __attribute__((ext_vector_type(8))) short s8v;
typedef __attribute__((ext_vector_type(4))) float f4v;

__device__ __forceinline__ short f2bs(float f) {
    bf16 h = __float2bfloat16(f);
    return __builtin_bit_cast(short, h);
}
__device__ __forceinline__ float bsToF(short s) {
    return __builtin_bit_cast(float, ((unsigned)(unsigned short)s) << 16);
}
__device__ __forceinline__ float loF(u32 v) { return bsToF((short)(v & 0xffff)); }
__device__ __forceinline__ float hiF(u32 v) { return bsToF((short)(v >> 16)); }
__device__ __forceinline__ u32 packbf(float a, float b) {
    return (u32)(unsigned short)f2bs(a) | ((u32)(unsigned short)f2bs(b) << 16);
}

// ---------------- player GEMM -> paired bf16 xl ----------------
__global__ void gemm_xl_kernel(const float* __restrict__ A, const float* __restrict__ W,
                               ushort* __restrict__ xlP, int M) {
    __shared__ float Al[16 * 128];
    const int tid = threadIdx.x;
    const int row0 = blockIdx.x * 16;
    for (int i = tid; i < 16 * 128; i += 256) {
        int r = row0 + (i >> 7);
        Al[i] = (r < M) ? A[(size_t)r * 128 + (i & 127)] : 0.f;
    }
    __syncthreads();
    const int col = tid & 127, rg = tid >> 7;
    float acc[8];
#pragma unroll
    for (int i = 0; i < 8; i++) acc[i] = 0.f;
    for (int k = 0; k < 128; k++) {
        float w = W[k * 128 + col];
#pragma unroll
        for (int i = 0; i < 8; i++) acc[i] += Al[(rg * 8 + i) * 128 + k] * w;
    }
    int pidx = (col & 63) * 2 + (col >> 6);  // paired position
#pragma unroll
    for (int i = 0; i < 8; i++) {
        int r = row0 + rg * 8 + i;
        if (r < M) xlP[(size_t)r * 128 + pidx] = (unsigned short)f2bs(acc[i]);
    }
}

// ---------------- hist + weight-transpose (independent work, one launch) ----------------
__global__ void hist_wt_kernel(const int* __restrict__ em, const int* __restrict__ ep,
                               const int* __restrict__ ei, int* __restrict__ counts,
                               const float* __restrict__ W0, const float* __restrict__ W1,
                               const float* __restrict__ W2, const float* __restrict__ W3,
                               const float* __restrict__ W4, ushort* __restrict__ Wt) {
    int t = blockIdx.x * 256 + threadIdx.x;
    if (t < 5 * 16384) {
        int w = t >> 14, r = t & 16383, k = r >> 7, n = r & 127;
        const float* W = (w == 0) ? W0 : (w == 1) ? W1 : (w == 2) ? W2 : (w == 3) ? W3 : W4;
        Wt[w * 16384 + n * 128 + k] = (unsigned short)f2bs(W[k * 128 + n]);
    }
    if (t < EM_N) atomicAdd(&counts[em[EM_N + t]], 1);
    else if (t < EM_N + EP_N) atomicAdd(&counts[NB + ep[EP_N + (t - EM_N)]], 1);
    else if (t < POOL_N) atomicAdd(&counts[2 * NB + ei[EI_N + (t - EM_N - EP_N)]], 1);
}

// ---------------- MFMA fused 5-matrix GEMM -> paired-bf16 outputs ----------------
__global__ __launch_bounds__(256) void gemm5_mfma_kernel(
    const float* __restrict__ A, const ushort* __restrict__ Wt,
    const float* __restrict__ bq, const float* __restrict__ bk,
    const float* __restrict__ bv_, const float* __restrict__ bskip,
    u32* __restrict__ xrP, u32* __restrict__ qP, u32* __restrict__ kvP,
    u32* __restrict__ skipP) {
    const int lane = threadIdx.x & 63;
    const int wv = threadIdx.x >> 6;
    const int quad = lane >> 4, l16 = lane & 15;
    const int mbase = blockIdx.x * 128 + wv * 32;

    s8v a[2][4];
#pragma unroll
    for (int mt = 0; mt < 2; mt++) {
        int row = mbase + mt * 16 + l16;
        if (row >= NB) row = NB - 1;
        const float* ap = A + (size_t)row * 128 + quad * 8;
#pragma unroll
        for (int kt = 0; kt < 4; kt++) {
            const float4* p = (const float4*)(ap + kt * 32);
            float4 u = p[0], v = p[1];
            s8v f;
            f[0] = f2bs(u.x); f[1] = f2bs(u.y); f[2] = f2bs(u.z); f[3] = f2bs(u.w);
            f[4] = f2bs(v.x); f[5] = f2bs(v.y); f[6] = f2bs(v.z); f[7] = f2bs(v.w);
            a[mt][kt] = f;
        }
    }

#pragma unroll
    for (int w = 0; w < 5; w++) {
        const ushort* wt = Wt + w * 16384;
        u32* op; const float* bp; int stride, obase;
        if (w == 0)      { op = xrP;   bp = nullptr; stride = 64;  obase = 0; }
        else if (w == 1) { op = qP;    bp = bq;      stride = 64;  obase = 0; }
        else if (w == 2) { op = kvP;   bp = bk;      stride = 128; obase = 0; }
        else if (w == 3) { op = kvP;   bp = bv_;     stride = 128; obase = 64; }
        else             { op = skipP; bp = bskip;   stride = 64;  obase = 0; }
#pragma unroll
        for (int np = 0; np < 4; np++) {
            int clo = np * 16 + l16, chi = clo + 64;
            s8v blo[4], bhi[4];
#pragma unroll
            for (int kt = 0; kt < 4; kt++) {
                blo[kt] = *(const s8v*)(wt + clo * 128 + kt * 32 + quad * 8);
                bhi[kt] = *(const s8v*)(wt + chi * 128 + kt * 32 + quad * 8);
            }
            float bvlo = bp ? bp[clo] : 0.f, bvhi = bp ? bp[chi] : 0.f;
#pragma unroll
            for (int mt = 0; mt < 2; mt++) {
                f4v alo = {0.f, 0.f, 0.f, 0.f}, ahi = {0.f, 0.f, 0.f, 0.f};
#pragma unroll
                for (int kt = 0; kt < 4; kt++) {
                    alo = __builtin_amdgcn_mfma_f32_16x16x32_bf16(a[mt][kt], blo[kt], alo, 0, 0, 0);
                    ahi = __builtin_amdgcn_mfma_f32_16x16x32_bf16(a[mt][kt], bhi[kt], ahi, 0, 0, 0);
                }
#pragma unroll
                for (int r = 0; r < 4; r++) {
                    int row = mbase + mt * 16 + quad * 4 + r;
                    if (row < NB)
                        op[(size_t)row * stride + obase + clo] = packbf(alo[r] + bvlo, ahi[r] + bvhi);
                }
            }
        }
    }
}

// ---------------- scan ----------------
__global__ void scan1_kernel(const int* __restrict__ counts, int* __restrict__ offsets,
                             int* __restrict__ partials) {
    __shared__ int sd[256];
    int b = blockIdx.x, tid = threadIdx.x;
    int base = b * SCAN_BLK + tid * 4;
    int v[4]; int ts = 0;
#pragma unroll
    for (int j = 0; j < 4; j++) { int idx = base + j; v[j] = (idx < SEG_TOT) ? counts[idx] : 0; ts += v[j]; }
    sd[tid] = ts;
    for (int off = 1; off < 256; off <<= 1) {
        __syncthreads(); int t = (tid >= off) ? sd[tid - off] : 0;
        __syncthreads(); sd[tid] += t;
    }
    int run = sd[tid] - ts;
#pragma unroll
    for (int j = 0; j < 4; j++) { int idx = base + j; if (idx < SEG_TOT) offsets[idx] = run; run += v[j]; }
    if (tid == 255) partials[b] = sd[255];
}

__global__ void scan2_kernel(int* __restrict__ partials) {
    __shared__ int sd[256];
    int tid = threadIdx.x;
    int v = (tid < NPART) ? partials[tid] : 0;
    sd[tid] = v;
    for (int off = 1; off < 256; off <<= 1) {
        __syncthreads(); int t = (tid >= off) ? sd[tid - off] : 0;
        __syncthreads(); sd[tid] += t;
    }
    if (tid < NPART) partials[tid] = sd[tid] - v;
}

__global__ void scan3_kernel(int* __restrict__ offsets, const int* __restrict__ partials,
                             int* __restrict__ cursors) {
    int t = blockIdx.x * 256 + threadIdx.x;
    if (t >= SEG_TOT) return;
    int o = offsets[t] + partials[t >> 10];
    offsets[t] = o;
    cursors[t] = o;
}

__global__ void fill_all_kernel(const int* __restrict__ em, const int* __restrict__ ep,
                                const int* __restrict__ ei, const float* __restrict__ ea_p,
                                int* __restrict__ cursors, int* __restrict__ psrc,
                                float* __restrict__ pea) {
    int t = blockIdx.x * 256 + threadIdx.x;
    int seg, s; float ea = 0.f;
    if (t < EM_N) { s = em[t]; seg = em[EM_N + t]; }
    else if (t < EM_N + EP_N) { int e = t - EM_N; s = ep[e]; seg = NB + ep[EP_N + e]; ea = ea_p[e]; }
    else if (t < POOL_N) { int e = t - EM_N - EP_N; s = ei[e]; seg = 2 * NB + ei[EI_N + e]; }
    else return;
    int pos = atomicAdd(&cursors[seg], 1);
    psrc[pos] = s; pea[pos] = ea;
}

// ---------------- per-edge bodies (wave-uniform control flow) ----------------
__device__ __forceinline__ void gat_edge(const u32* __restrict__ xlP, int s, int l,
                                         float xr0, float xr1, float at0, float at1,
                                         float& x0, float& x1, float& p0, float& p1) {
    u32 xv = xlP[(size_t)s * 64 + l];
    x0 = loF(xv); x1 = hiF(xv);
    float u0 = x0 + xr0; u0 = u0 > 0.f ? u0 : 0.2f * u0;
    float u1 = x1 + xr1; u1 = u1 > 0.f ? u1 : 0.2f * u1;
    p0 = u0 * at0; p1 = u1 * at1;
#pragma unroll
    for (int m = 1; m <= 16; m <<= 1) { p0 += __shfl_xor(p0, m); p1 += __shfl_xor(p1, m); }
    p0 = __expf(p0); p1 = __expf(p1);
}

__device__ __forceinline__ void tr_edge(const u32* __restrict__ kvP, int s, int l, float ea,
                                        float q0, float q1, float w0, float w1,
                                        float& v0, float& v1, float& p0, float& p1) {
    u32 kk = kvP[(size_t)s * 128 + l];
    u32 vv = kvP[(size_t)s * 128 + 64 + l];
    p0 = q0 * (loF(kk) + ea * w0);
    p1 = q1 * (hiF(kk) + ea * w1);
#pragma unroll
    for (int m = 1; m <= 16; m <<= 1) { p0 += __shfl_xor(p0, m); p1 += __shfl_xor(p1, m); }
    p0 = __expf(p0 * 0.17677669529663687f);
    p1 = __expf(p1 * 0.17677669529663687f);
    v0 = loF(vv); v1 = hiF(vv);
}

// ---------------- fused ball kernel: GAT + TR + skip + residual + LN ----------------
__global__ __launch_bounds__(256) void ball_fused_kernel(
    const u32* __restrict__ xlP, const u32* __restrict__ xrP, const u32* __restrict__ qP,
    const u32* __restrict__ kvP, const u32* __restrict__ skipP,
    const float* __restrict__ x_ball, const float* __restrict__ g_att, const float* __restrict__ g_b,
    const float* __restrict__ We,
    const int* __restrict__ offsets, const int* __restrict__ counts,
    const int* __restrict__ psrc, const float* __restrict__ pea,
    const float* __restrict__ ln_g, const float* __restrict__ ln_b, float* __restrict__ out) {
    const int wv = threadIdx.x >> 6, l = threadIdx.x & 63;
    const int d = blockIdx.x * 4 + wv;
    if (d >= NB) return;
    const size_t rowD = (size_t)d * 128;

    // ---- GATv2 ----
    u32 xr2 = xrP[(size_t)d * 64 + l];
    float xr0 = loF(xr2), xr1 = hiF(xr2);
    float at0 = g_att[l], at1 = g_att[l + 64];
    int beg = offsets[d], cnt = counts[d];
    float n0 = 0.f, n1 = 0.f, de0 = 0.f, de1 = 0.f;
    int j = 0;
    for (; j + 1 < cnt; j += 2) {
        int sA = psrc[beg + j], sB = psrc[beg + j + 1];
        float xa0, xa1, pa0, pa1, xb0, xb1, pb0, pb1;
        gat_edge(xlP, sA, l, xr0, xr1, at0, at1, xa0, xa1, pa0, pa1);
        gat_edge(xlP, sB, l, xr0, xr1, at0, at1, xb0, xb1, pb0, pb1);
        n0 += pa0 * xa0 + pb0 * xb0; n1 += pa1 * xa1 + pb1 * xb1;
        de0 += pa0 + pb0; de1 += pa1 + pb1;
    }
    if (j < cnt) {
        int s = psrc[beg + j];
        float x0, x1, p0, p1;
        gat_edge(xlP, s, l, xr0, xr1, at0, at1, x0, x1, p0, p1);
        n0 += p0 * x0; n1 += p1 * x1; de0 += p0; de1 += p1;
    }
    float gat0 = n0 / (de0 + 1e-16f), gat1 = n1 / (de1 + 1e-16f);

    // ---- TransformerConv ----
    u32 q2 = qP[(size_t)d * 64 + l];
    float q0 = loF(q2), q1 = hiF(q2);
    float w0 = We[l], w1 = We[l + 64];
    beg = offsets[NB + d]; cnt = counts[NB + d];
    float sv0 = 0.f, sv1 = 0.f, sp0 = 0.f, sp1 = 0.f;
    de0 = de1 = 0.f;
    j = 0;
    for (; j + 1 < cnt; j += 2) {
        int sA = psrc[beg + j], sB = psrc[beg + j + 1];
        float eaA = pea[beg + j], eaB = pea[beg + j + 1];
        float va0, va1, pa0, pa1, vb0, vb1, pb0, pb1;
        tr_edge(kvP, sA, l, eaA, q0, q1, w0, w1, va0, va1, pa0, pa1);
        tr_edge(kvP, sB, l, eaB, q0, q1, w0, w1, vb0, vb1, pb0, pb1);
        sv0 += pa0 * va0 + pb0 * vb0; sv1 += pa1 * va1 + pb1 * vb1;
        sp0 += pa0 * eaA + pb0 * eaB; sp1 += pa1 * eaA + pb1 * eaB;
        de0 += pa0 + pb0; de1 += pa1 + pb1;
    }
    if (j < cnt) {
        int s = psrc[beg + j];
        float ea = pea[beg + j];
        float v0, v1, p0, p1;
        tr_edge(kvP, s, l, ea, q0, q1, w0, w1, v0, v1, p0, p1);
        sv0 += p0 * v0; sv1 += p1 * v1;
        sp0 += p0 * ea; sp1 += p1 * ea;
        de0 += p0; de1 += p1;
    }
    float tr0 = (sv0 + sp0 * w0) / (de0 + 1e-16f);
    float tr1 = (sv1 + sp1 * w1) / (de1 + 1e-16f);

    // ---- skip + residual + LayerNorm ----
    u32 sk = skipP[(size_t)d * 64 + l];
    float val0 = loF(sk) + gat0 + tr0 + x_ball[rowD + l] + g_b[l];
    float val1 = hiF(sk) + gat1 + tr1 + x_ball[rowD + l + 64] + g_b[l + 64];
    float s = val0 + val1;
#pragma unroll
    for (int m = 1; m <= 32; m <<= 1) s += __shfl_xor(s, m);
    float mu = s * (1.f / 128.f);
    float d0 = val0 - mu, d1 = val1 - mu;
    float qv = d0 * d0 + d1 * d1;
#pragma unroll
    for (int m = 1; m <= 32; m <<= 1) qv += __shfl_xor(qv, m);
    float inv = rsqrtf(qv * (1.f / 128.f) + 1e-5f);
    out[rowD + l] = d0 * inv * ln_g[l] + ln_b[l];
    out[rowD + l + 64] = d1 * inv * ln_g[l + 64] + ln_b[l + 64];
}

// ---------------- SAGE gather, 4-way edge split per node ----------------
__global__ void sage_gather4_kernel(const float* __restrict__ x_ball,
                                    const int* __restrict__ offsets, const int* __restrict__ counts,
                                    const int* __restrict__ psrc, float* __restrict__ summ) {
    __shared__ float part[4][128];
    int c = blockIdx.x;
    int w = threadIdx.x >> 6, l = threadIdx.x & 63;
    int beg = offsets[2 * NB + c], cnt = counts[2 * NB + c];
    float s0 = 0.f, s1 = 0.f;
    for (int j = w; j < cnt; j += 4) {
        int s = psrc[beg + j];
        size_t rs = (size_t)s * 128;
        s0 += x_ball[rs + l];
        s1 += x_ball[rs + l + 64];
    }
    part[w][l] = s0; part[w][l + 64] = s1;
    __syncthreads();
    if (w == 0) {
        float m = fmaxf((float)cnt, 1.f);
        size_t rowC = (size_t)c * 128;
        summ[rowC + l] = (part[0][l] + part[1][l] + part[2][l] + part[3][l]) / m;
        summ[rowC + l + 64] = (part[0][l + 64] + part[1][l + 64] + part[2][l + 64] + part[3][l + 64]) / m;
    }
}

// ---------------- fused ctx: xc@Wr + summ@Wl + bl + residual + LN ----------------
__global__ void ctx_fused_kernel(const float* __restrict__ xc, const float* __restrict__ summ,
                                 const float* __restrict__ Wr, const float* __restrict__ Wl,
                                 const float* __restrict__ bl,
                                 const float* __restrict__ g, const float* __restrict__ b,
                                 float* __restrict__ out) {
    __shared__ float A0[16 * 128];
    __shared__ float A1[16 * 128];
    __shared__ float CB[16 * 128];
    const int tid = threadIdx.x;
    const int row0 = blockIdx.x * 16;
    for (int i = tid; i < 16 * 128; i += 256) {
        int r = row0 + (i >> 7);
        A0[i] = (r < NC) ? xc[(size_t)r * 128 + (i & 127)] : 0.f;
        A1[i] = (r < NC) ? summ[(size_t)r * 128 + (i & 127)] : 0.f;
    }
    __syncthreads();
    const int col = tid & 127, rg = tid >> 7;
    float acc[8];
#pragma unroll
    for (int i = 0; i < 8; i++) acc[i] = 0.f;
    for (int k = 0; k < 128; k++) {
        float w0 = Wr[k * 128 + col], w1 = Wl[k * 128 + col];
#pragma unroll
        for (int i = 0; i < 8; i++)
            acc[i] += A0[(rg * 8 + i) * 128 + k] * w0 + A1[(rg * 8 + i) * 128 + k] * w1;
    }
    float bv = bl[col];
#pragma unroll
    for (int i = 0; i < 8; i++)
        CB[(rg * 8 + i) * 128 + col] = acc[i] + bv + A0[(rg * 8 + i) * 128 + col];
    __syncthreads();
    const int wv = tid >> 6, l = tid & 63;
    for (int r = 0; r < 4; r++) {
        int lr = wv * 4 + r, row = row0 + lr;
        if (row >= NC) break;
        float v0 = CB[lr * 128 + l], v1 = CB[lr * 128 + l + 64];
        float s = v0 + v1;
#pragma unroll
        for (int m = 1; m <= 32; m <<= 1) s += __shfl_xor(s, m);
        float mu = s * (1.f / 128.f);
        float d0 = v0 - mu, d1 = v1 - mu;
        float qv = d0 * d0 + d1 * d1;
#pragma unroll
        for (int m = 1; m <= 32; m <<= 1) qv += __shfl_xor(qv, m);
        float inv = rsqrtf(qv * (1.f / 128.f) + 1e-5f);
        out[(size_t)row * 128 + l] = d0 * inv * g[l] + b[l];
        out[(size_t)row * 128 + l + 64] = d1 * inv * g[l + 64] + b[l + 64];
    }
}

__global__ void copy_player_kernel(const float* __restrict__ xp, float* __restrict__ out) {
    int t = blockIdx.x * 256 + threadIdx.x;
    if (t >= NP * 128) return;
    out[t] = xp[t];
}

extern "C" void kernel_launch(void* const* d_in, const int* in_sizes, int n_in,
                              void* d_out, int out_size, void* d_ws, size_t ws_size,
                              hipStream_t stream) {
    const float* x_ball = (const float*)d_in[0];
    const float* x_player = (const float*)d_in[1];
    const float* x_context = (const float*)d_in[2];
    const int* em = (const int*)d_in[3];
    const int* ep = (const int*)d_in[4];
    const int* ei = (const int*)d_in[5];
    const float* ea_p = (const float*)d_in[6];
    const float* g_Wl = (const float*)d_in[7];
    const float* g_Wr = (const float*)d_in[8];
    const float* g_att = (const float*)d_in[9];
    const float* g_b = (const float*)d_in[10];
    const float* t_Wq = (const float*)d_in[11];
    const float* t_bq = (const float*)d_in[12];
    const float* t_Wk = (const float*)d_in[13];
    const float* t_bk = (const float*)d_in[14];
    const float* t_Wv = (const float*)d_in[15];
    const float* t_bv = (const float*)d_in[16];
    const float* t_We = (const float*)d_in[17];
    const float* t_Wskip = (const float*)d_in[18];
    const float* t_bskip = (const float*)d_in[19];
    const float* s_Wl = (const float*)d_in[20];
    const float* s_bl = (const float*)d_in[21];
    const float* s_Wr = (const float*)d_in[22];
    const float* ln_ball_g = (const float*)d_in[23];
    const float* ln_ball_b = (const float*)d_in[24];
    const float* ln_ctx_g = (const float*)d_in[25];
    const float* ln_ctx_b = (const float*)d_in[26];
    float* out = (float*)d_out;

    // ---- workspace (~86 MB) ----
    float* ws = (float*)d_ws;
    size_t o = 0;
    float* summ = ws + o;     o += (size_t)NC * 128;
    float* pea = ws + o;      o += POOL_N;
    int* counts = (int*)(ws + o);   o += SEG_TOT;
    int* offsets = (int*)(ws + o);  o += SEG_TOT;
    int* cursors = (int*)(ws + o);  o += SEG_TOT;
    int* partials = (int*)(ws + o); o += 128;
    int* psrc = (int*)(ws + o);     o += POOL_N;
    ushort* Wt = (ushort*)(ws + o); o += (5 * 16384) / 2;
    u32* xlP = (u32*)(ws + o);      o += (size_t)NP * 64;
    u32* xrP = (u32*)(ws + o);      o += (size_t)NB * 64;
    u32* qP = (u32*)(ws + o);       o += (size_t)NB * 64;
    u32* kvP = (u32*)(ws + o);      o += (size_t)NB * 128;
    u32* skipP = (u32*)(ws + o);    o += (size_t)NB * 64;

    dim3 blk(256);
    // ---- CSR build (+ weight transpose folded into hist) ----
    hipMemsetAsync(counts, 0, SEG_TOT * sizeof(int), stream);
    hist_wt_kernel<<<(POOL_N + 255) / 256, blk, 0, stream>>>(em, ep, ei, counts,
                                                             g_Wr, t_Wq, t_Wk, t_Wv, t_Wskip, Wt);
    scan1_kernel<<<NPART, blk, 0, stream>>>(counts, offsets, partials);
    scan2_kernel<<<1, blk, 0, stream>>>(partials);
    scan3_kernel<<<(SEG_TOT + 255) / 256, blk, 0, stream>>>(offsets, partials, cursors);
    fill_all_kernel<<<(POOL_N + 255) / 256, blk, 0, stream>>>(em, ep, ei, ea_p, cursors, psrc, pea);

    // ---- dense projections ----
    gemm_xl_kernel<<<(NP + 15) / 16, blk, 0, stream>>>(x_player, g_Wl, (ushort*)xlP, NP);
    gemm5_mfma_kernel<<<(NB + 127) / 128, blk, 0, stream>>>(x_ball, Wt, t_bq, t_bk, t_bv, t_bskip,
                                                            xrP, qP, kvP, skipP);

    // ---- fused ball pipeline ----
    ball_fused_kernel<<<(NB + 3) / 4, blk, 0, stream>>>(
        xlP, xrP, qP, kvP, skipP, x_ball, g_att, g_b, t_We,
        offsets, counts, psrc, pea, ln_ball_g, ln_ball_b, out);

    // ---- SAGE -> ctx ----
    sage_gather4_kernel<<<NC, blk, 0, stream>>>(x_ball, offsets, counts, psrc, summ);
    ctx_fused_kernel<<<(NC + 15) / 16, blk, 0, stream>>>(x_context, summ, s_Wr, s_Wl, s_bl,
                                                         ln_ctx_g, ln_ctx_b, out + (size_t)NB * 128);
    copy_player_kernel<<<(NP * 128 + 255) / 256, blk, 0, stream>>>(x_player,
                                                                   out + (size_t)(NB + NC) * 128);
}

// Round 9
// 353.798 us; speedup vs baseline: 1.3992x; 1.0710x over previous
//
#include <hip/hip_runtime.h>
#include <hip/hip_bf16.h>

#define NB 60000
#define NP 2000
#define NC 4000
#define EM_N 150000
#define EP_N 300000
#define EI_N 150000
#define POOL_N (EM_N + EP_N + EI_N)
#define SEG_TOT (NB + NB + NC)
#define SCAN_BLK 1024
#define NPART ((SEG_TOT + SCAN_BLK - 1) / SCAN_BLK)   // 122
#define BALL_BLKS ((NB + 127) / 128)                  // 469
#define PLYR_BLKS ((NP + 127) / 128)                  // 16

typedef __hip_bfloat16 bf16;
typedef unsigned int u32;
typedef __attribute__((ext_vector_type(8))) short s8v;
typedef __attribute__((ext_vector_type(4))) float f4v;

__device__ __forceinline__ short f2bs(float f) {
    bf16 h = __float2bfloat16(f);
    return __builtin_bit_cast(short, h);
}
__device__ __forceinline__ float bsToF(short s) {
    return __builtin_bit_cast(float, ((unsigned)(unsigned short)s) << 16);
}
__device__ __forceinline__ float loF(u32 v) { return bsToF((short)(v & 0xffff)); }
__device__ __forceinline__ float hiF(u32 v) { return bsToF((short)(v >> 16)); }
__device__ __forceinline__ u32 packbf(float a, float b) {
    return (u32)(unsigned short)f2bs(a) | ((u32)(unsigned short)f2bs(b) << 16);
}

// ---------------- hist + 6-weight transpose (independent work, one launch) ----------------
// Wt column permutation: actual col n -> store_col = (n>>5)*32 + (n&1)*16 + ((n&31)>>1)
// so MFMA lane l16 of frag-lo/frag-hi yields actual cols 2*l16 / 2*l16+1 of each 32-col tile.
__global__ void hist_wt_kernel(const int* __restrict__ em, const int* __restrict__ ep,
                               const int* __restrict__ ei, int* __restrict__ counts,
                               const float* __restrict__ W0, const float* __restrict__ W1,
                               const float* __restrict__ W2, const float* __restrict__ W3,
                               const float* __restrict__ W4, const float* __restrict__ W5,
                               ushort* __restrict__ Wt) {
    int t = blockIdx.x * 256 + threadIdx.x;
    if (t < 6 * 16384) {
        int w = t >> 14, r = t & 16383, k = r >> 7, n = r & 127;
        const float* W = (w == 0) ? W0 : (w == 1) ? W1 : (w == 2) ? W2 : (w == 3) ? W3
                       : (w == 4) ? W4 : W5;
        int sc = (n >> 5) * 32 + ((n & 1) << 4) + ((n & 31) >> 1);
        Wt[w * 16384 + sc * 128 + k] = (unsigned short)f2bs(W[k * 128 + n]);
    }
    if (t < EM_N) atomicAdd(&counts[em[EM_N + t]], 1);
    else if (t < EM_N + EP_N) atomicAdd(&counts[NB + ep[EP_N + (t - EM_N)]], 1);
    else if (t < POOL_N) atomicAdd(&counts[2 * NB + ei[EI_N + (t - EM_N - EP_N)]], 1);
}

// ---------------- MFMA fused 6-matrix GEMM: ball rows (5 weights) + player rows (1 weight) ----
// Outputs paired (2l,2l+1)-bf16: xr,q,skip,xl stride 64 u32; kv stride 128 u32 with per-lane
// (k-pair, v-pair) adjacent.
__global__ __launch_bounds__(256) void gemm6_mfma_kernel(
    const float* __restrict__ Aball, const float* __restrict__ Aplyr,
    const ushort* __restrict__ Wt,
    const float* __restrict__ bq, const float* __restrict__ bk,
    const float* __restrict__ bv_, const float* __restrict__ bskip,
    u32* __restrict__ xrP, u32* __restrict__ qP, u32* __restrict__ kvP,
    u32* __restrict__ skipP, u32* __restrict__ xlP) {
    const int lane = threadIdx.x & 63;
    const int wv = threadIdx.x >> 6;
    const int quad = lane >> 4, l16 = lane & 15;
    const bool plyr = (blockIdx.x >= BALL_BLKS);
    const int M = plyr ? NP : NB;
    const float* A = plyr ? Aplyr : Aball;
    const int mbase = (plyr ? (blockIdx.x - BALL_BLKS) : blockIdx.x) * 128 + wv * 32;

    s8v a[2][4];
#pragma unroll
    for (int mt = 0; mt < 2; mt++) {
        int row = mbase + mt * 16 + l16;
        if (row >= M) row = M - 1;
        const float* ap = A + (size_t)row * 128 + quad * 8;
#pragma unroll
        for (int kt = 0; kt < 4; kt++) {
            const float4* p = (const float4*)(ap + kt * 32);
            float4 u = p[0], v = p[1];
            s8v f;
            f[0] = f2bs(u.x); f[1] = f2bs(u.y); f[2] = f2bs(u.z); f[3] = f2bs(u.w);
            f[4] = f2bs(v.x); f[5] = f2bs(v.y); f[6] = f2bs(v.z); f[7] = f2bs(v.w);
            a[mt][kt] = f;
        }
    }

    const int wbeg = plyr ? 5 : 0, wend = plyr ? 6 : 5;
    for (int w = wbeg; w < wend; w++) {
        const ushort* wt = Wt + w * 16384;
        u32* op; const float* bp; int stride, obase;
        if (w == 0)      { op = xrP;   bp = nullptr; stride = 64;  obase = 0; }
        else if (w == 1) { op = qP;    bp = bq;      stride = 64;  obase = 0; }
        else if (w == 2) { op = kvP;   bp = bk;      stride = 128; obase = 0; }
        else if (w == 3) { op = kvP;   bp = bv_;     stride = 128; obase = 1; }
        else if (w == 4) { op = skipP; bp = bskip;   stride = 64;  obase = 0; }
        else             { op = xlP;   bp = nullptr; stride = 64;  obase = 0; }
        const int kvmul = (stride == 128) ? 2 : 1;
#pragma unroll
        for (int t = 0; t < 4; t++) {
            s8v blo[4], bhi[4];
#pragma unroll
            for (int kt = 0; kt < 4; kt++) {
                blo[kt] = *(const s8v*)(wt + (t * 32 + l16) * 128 + kt * 32 + quad * 8);
                bhi[kt] = *(const s8v*)(wt + (t * 32 + 16 + l16) * 128 + kt * 32 + quad * 8);
            }
            float bvlo = 0.f, bvhi = 0.f;
            if (bp) { float2 b2 = ((const float2*)bp)[t * 16 + l16]; bvlo = b2.x; bvhi = b2.y; }
#pragma unroll
            for (int mt = 0; mt < 2; mt++) {
                f4v alo = {0.f, 0.f, 0.f, 0.f}, ahi = {0.f, 0.f, 0.f, 0.f};
#pragma unroll
                for (int kt = 0; kt < 4; kt++) {
                    alo = __builtin_amdgcn_mfma_f32_16x16x32_bf16(a[mt][kt], blo[kt], alo, 0, 0, 0);
                    ahi = __builtin_amdgcn_mfma_f32_16x16x32_bf16(a[mt][kt], bhi[kt], ahi, 0, 0, 0);
                }
#pragma unroll
                for (int r = 0; r < 4; r++) {
                    int row = mbase + mt * 16 + quad * 4 + r;
                    if (row < M)
                        op[(size_t)row * stride + (t * 16 + l16) * kvmul + obase]
                            = packbf(alo[r] + bvlo, ahi[r] + bvhi);
                }
            }
        }
    }
}

// ---------------- scan ----------------
__global__ void scan1_kernel(const int* __restrict__ counts, int* __restrict__ offsets,
                             int* __restrict__ partials) {
    __shared__ int sd[256];
    int b = blockIdx.x, tid = threadIdx.x;
    int base = b * SCAN_BLK + tid * 4;
    int v[4]; int ts = 0;
#pragma unroll
    for (int j = 0; j < 4; j++) { int idx = base + j; v[j] = (idx < SEG_TOT) ? counts[idx] : 0; ts += v[j]; }
    sd[tid] = ts;
    for (int off = 1; off < 256; off <<= 1) {
        __syncthreads(); int t = (tid >= off) ? sd[tid - off] : 0;
        __syncthreads(); sd[tid] += t;
    }
    int run = sd[tid] - ts;
#pragma unroll
    for (int j = 0; j < 4; j++) { int idx = base + j; if (idx < SEG_TOT) offsets[idx] = run; run += v[j]; }
    if (tid == 255) partials[b] = sd[255];
}

// scan2+scan3 merged: every block redundantly scans the 122 partials, then applies its base.
__global__ void scan23_kernel(int* __restrict__ offsets, const int* __restrict__ partials,
                              int* __restrict__ cursors) {
    __shared__ int sd[256];
    int b = blockIdx.x, tid = threadIdx.x;
    int v = (tid < NPART) ? partials[tid] : 0;
    sd[tid] = v;
    for (int off = 1; off < 256; off <<= 1) {
        __syncthreads(); int t = (tid >= off) ? sd[tid - off] : 0;
        __syncthreads(); sd[tid] += t;
    }
    __syncthreads();
    int basev = (b == 0) ? 0 : sd[b - 1];  // exclusive prefix for this block
    int base = b * SCAN_BLK + tid * 4;
#pragma unroll
    for (int j = 0; j < 4; j++) {
        int idx = base + j;
        if (idx < SEG_TOT) {
            int o = offsets[idx] + basev;
            offsets[idx] = o;
            cursors[idx] = o;
        }
    }
}

__global__ void fill_all_kernel(const int* __restrict__ em, const int* __restrict__ ep,
                                const int* __restrict__ ei, const float* __restrict__ ea_p,
                                int* __restrict__ cursors, int2* __restrict__ pool) {
    int t = blockIdx.x * 256 + threadIdx.x;
    int seg, s; float ea = 0.f;
    if (t < EM_N) { s = em[t]; seg = em[EM_N + t]; }
    else if (t < EM_N + EP_N) { int e = t - EM_N; s = ep[e]; seg = NB + ep[EP_N + e]; ea = ea_p[e]; }
    else if (t < POOL_N) { int e = t - EM_N - EP_N; s = ei[e]; seg = 2 * NB + ei[EI_N + e]; }
    else return;
    int pos = atomicAdd(&cursors[seg], 1);
    pool[pos] = make_int2(s, __float_as_int(ea));
}

// ---------------- fused ball kernel: GAT + TR + skip + residual + LN ----------------
// Pairing (2l, 2l+1): both elems in head l>>4 -> 4-level/16-lane logit reduction, ONE exp.
__global__ __launch_bounds__(256) void ball_fused_kernel(
    const u32* __restrict__ xlP, const u32* __restrict__ xrP, const u32* __restrict__ qP,
    const u32* __restrict__ kvP, const u32* __restrict__ skipP,
    const float* __restrict__ x_ball, const float* __restrict__ g_att, const float* __restrict__ g_b,
    const float* __restrict__ We,
    const int* __restrict__ offsets, const int* __restrict__ counts,
    const int2* __restrict__ pool,
    const float* __restrict__ ln_g, const float* __restrict__ ln_b, float* __restrict__ out) {
    const int wv = threadIdx.x >> 6, l = threadIdx.x & 63;
    const int d = blockIdx.x * 4 + wv;
    if (d >= NB) return;
    const size_t rowD = (size_t)d * 64;   // in pair units

    // ---- GATv2 (player -> ball) ----
    float2 att = ((const float2*)g_att)[l];
    u32 xr2 = xrP[rowD + l];
    float xr0 = loF(xr2), xr1 = hiF(xr2);
    int beg = offsets[d], cnt = counts[d];
    float n0 = 0.f, n1 = 0.f, deg = 0.f;
    int j = 0;
    for (; j + 1 < cnt; j += 2) {
        int sA = pool[beg + j].x, sB = pool[beg + j + 1].x;
        u32 xa = xlP[(size_t)sA * 64 + l], xb = xlP[(size_t)sB * 64 + l];
        float xa0 = loF(xa), xa1 = hiF(xa), xb0 = loF(xb), xb1 = hiF(xb);
        float ua0 = xa0 + xr0; ua0 = ua0 > 0.f ? ua0 : 0.2f * ua0;
        float ua1 = xa1 + xr1; ua1 = ua1 > 0.f ? ua1 : 0.2f * ua1;
        float ub0 = xb0 + xr0; ub0 = ub0 > 0.f ? ub0 : 0.2f * ub0;
        float ub1 = xb1 + xr1; ub1 = ub1 > 0.f ? ub1 : 0.2f * ub1;
        float pa = ua0 * att.x + ua1 * att.y;
        float pb = ub0 * att.x + ub1 * att.y;
#pragma unroll
        for (int m = 1; m <= 8; m <<= 1) { pa += __shfl_xor(pa, m); pb += __shfl_xor(pb, m); }
        pa = __expf(pa); pb = __expf(pb);
        n0 += pa * xa0 + pb * xb0; n1 += pa * xa1 + pb * xb1; deg += pa + pb;
    }
    if (j < cnt) {
        int s = pool[beg + j].x;
        u32 xv = xlP[(size_t)s * 64 + l];
        float x0 = loF(xv), x1 = hiF(xv);
        float u0 = x0 + xr0; u0 = u0 > 0.f ? u0 : 0.2f * u0;
        float u1 = x1 + xr1; u1 = u1 > 0.f ? u1 : 0.2f * u1;
        float p = u0 * att.x + u1 * att.y;
#pragma unroll
        for (int m = 1; m <= 8; m <<= 1) p += __shfl_xor(p, m);
        p = __expf(p);
        n0 += p * x0; n1 += p * x1; deg += p;
    }
    float gat0 = n0 / (deg + 1e-16f), gat1 = n1 / (deg + 1e-16f);

    // ---- TransformerConv (ball -> ball) ----
    u32 q2 = qP[rowD + l];
    float q0 = loF(q2), q1 = hiF(q2);
    float2 we = ((const float2*)We)[l];
    float dw = q0 * we.x + q1 * we.y;     // q . We per head (hoisted)
#pragma unroll
    for (int m = 1; m <= 8; m <<= 1) dw += __shfl_xor(dw, m);
    beg = offsets[NB + d]; cnt = counts[NB + d];
    float sv0 = 0.f, sv1 = 0.f, spe = 0.f, det = 0.f;
    const uint2* kv2p = (const uint2*)kvP;
    j = 0;
    for (; j + 1 < cnt; j += 2) {
        int2 prA = pool[beg + j], prB = pool[beg + j + 1];
        float eaA = __int_as_float(prA.y), eaB = __int_as_float(prB.y);
        uint2 kvA = kv2p[(size_t)prA.x * 64 + l];
        uint2 kvB = kv2p[(size_t)prB.x * 64 + l];
        float pa = q0 * loF(kvA.x) + q1 * hiF(kvA.x);
        float pb = q0 * loF(kvB.x) + q1 * hiF(kvB.x);
#pragma unroll
        for (int m = 1; m <= 8; m <<= 1) { pa += __shfl_xor(pa, m); pb += __shfl_xor(pb, m); }
        pa = __expf((pa + eaA * dw) * 0.17677669529663687f);
        pb = __expf((pb + eaB * dw) * 0.17677669529663687f);
        sv0 += pa * loF(kvA.y) + pb * loF(kvB.y);
        sv1 += pa * hiF(kvA.y) + pb * hiF(kvB.y);
        spe += pa * eaA + pb * eaB;
        det += pa + pb;
    }
    if (j < cnt) {
        int2 pr = pool[beg + j];
        float ea = __int_as_float(pr.y);
        uint2 kv = kv2p[(size_t)pr.x * 64 + l];
        float p = q0 * loF(kv.x) + q1 * hiF(kv.x);
#pragma unroll
        for (int m = 1; m <= 8; m <<= 1) p += __shfl_xor(p, m);
        p = __expf((p + ea * dw) * 0.17677669529663687f);
        sv0 += p * loF(kv.y); sv1 += p * hiF(kv.y);
        spe += p * ea; det += p;
    }
    float tr0 = (sv0 + spe * we.x) / (det + 1e-16f);
    float tr1 = (sv1 + spe * we.y) / (det + 1e-16f);

    // ---- skip + residual + LayerNorm ----
    u32 sk = skipP[rowD + l];
    float2 xb2 = ((const float2*)x_ball)[rowD + l];
    float2 gb2 = ((const float2*)g_b)[l];
    float val0 = loF(sk) + gat0 + tr0 + xb2.x + gb2.x;
    float val1 = hiF(sk) + gat1 + tr1 + xb2.y + gb2.y;
    float s = val0 + val1;
#pragma unroll
    for (int m = 1; m <= 32; m <<= 1) s += __shfl_xor(s, m);
    float mu = s * (1.f / 128.f);
    float d0 = val0 - mu, d1 = val1 - mu;
    float qv = d0 * d0 + d1 * d1;
#pragma unroll
    for (int m = 1; m <= 32; m <<= 1) qv += __shfl_xor(qv, m);
    float inv = rsqrtf(qv * (1.f / 128.f) + 1e-5f);
    float2 g2 = ((const float2*)ln_g)[l];
    float2 b2 = ((const float2*)ln_b)[l];
    float2 o2 = make_float2(d0 * inv * g2.x + b2.x, d1 * inv * g2.y + b2.y);
    ((float2*)out)[rowD + l] = o2;
}

// ---------------- SAGE gather, 4-way edge split per node ----------------
__global__ void sage_gather4_kernel(const float* __restrict__ x_ball,
                                    const int* __restrict__ offsets, const int* __restrict__ counts,
                                    const int2* __restrict__ pool, float* __restrict__ summ) {
    __shared__ float part[4][128];
    int c = blockIdx.x;
    int w = threadIdx.x >> 6, l = threadIdx.x & 63;
    int beg = offsets[2 * NB + c], cnt = counts[2 * NB + c];
    float s0 = 0.f, s1 = 0.f;
    for (int j = w; j < cnt; j += 4) {
        int s = pool[beg + j].x;
        float2 xv = ((const float2*)x_ball)[(size_t)s * 64 + l];
        s0 += xv.x; s1 += xv.y;
    }
    part[w][l * 2] = s0; part[w][l * 2 + 1] = s1;
    __syncthreads();
    if (w == 0) {
        float m = fmaxf((float)cnt, 1.f);
        size_t rowC = (size_t)c * 128;
        summ[rowC + l * 2] = (part[0][l * 2] + part[1][l * 2] + part[2][l * 2] + part[3][l * 2]) / m;
        summ[rowC + l * 2 + 1] = (part[0][l * 2 + 1] + part[1][l * 2 + 1] + part[2][l * 2 + 1] + part[3][l * 2 + 1]) / m;
    }
}

// ---------------- fused ctx: xc@Wr + summ@Wl + bl + residual + LN ----------------
__global__ void ctx_fused_kernel(const float* __restrict__ xc, const float* __restrict__ summ,
                                 const float* __restrict__ Wr, const float* __restrict__ Wl,
                                 const float* __restrict__ bl,
                                 const float* __restrict__ g, const float* __restrict__ b,
                                 float* __restrict__ out) {
    __shared__ float A0[16 * 128];
    __shared__ float A1[16 * 128];
    __shared__ float CB[16 * 128];
    const int tid = threadIdx.x;
    const int row0 = blockIdx.x * 16;
    for (int i = tid; i < 16 * 128; i += 256) {
        int r = row0 + (i >> 7);
        A0[i] = (r < NC) ? xc[(size_t)r * 128 + (i & 127)] : 0.f;
        A1[i] = (r < NC) ? summ[(size_t)r * 128 + (i & 127)] : 0.f;
    }
    __syncthreads();
    const int col = tid & 127, rg = tid >> 7;
    float acc[8];
#pragma unroll
    for (int i = 0; i < 8; i++) acc[i] = 0.f;
    for (int k = 0; k < 128; k++) {
        float w0 = Wr[k * 128 + col], w1 = Wl[k * 128 + col];
#pragma unroll
        for (int i = 0; i < 8; i++)
            acc[i] += A0[(rg * 8 + i) * 128 + k] * w0 + A1[(rg * 8 + i) * 128 + k] * w1;
    }
    float bv = bl[col];
#pragma unroll
    for (int i = 0; i < 8; i++)
        CB[(rg * 8 + i) * 128 + col] = acc[i] + bv + A0[(rg * 8 + i) * 128 + col];
    __syncthreads();
    const int wv = tid >> 6, l = tid & 63;
    for (int r = 0; r < 4; r++) {
        int lr = wv * 4 + r, row = row0 + lr;
        if (row >= NC) break;
        float v0 = CB[lr * 128 + l], v1 = CB[lr * 128 + l + 64];
        float s = v0 + v1;
#pragma unroll
        for (int m = 1; m <= 32; m <<= 1) s += __shfl_xor(s, m);
        float mu = s * (1.f / 128.f);
        float d0 = v0 - mu, d1 = v1 - mu;
        float qv = d0 * d0 + d1 * d1;
#pragma unroll
        for (int m = 1; m <= 32; m <<= 1) qv += __shfl_xor(qv, m);
        float inv = rsqrtf(qv * (1.f / 128.f) + 1e-5f);
        out[(size_t)row * 128 + l] = d0 * inv * g[l] + b[l];
        out[(size_t)row * 128 + l + 64] = d1 * inv * g[l + 64] + b[l + 64];
    }
}

__global__ void copy_player_kernel(const float* __restrict__ xp, float* __restrict__ out) {
    int t = blockIdx.x * 256 + threadIdx.x;
    if (t >= NP * 128) return;
    out[t] = xp[t];
}

extern "C" void kernel_launch(void* const* d_in, const int* in_sizes, int n_in,
                              void* d_out, int out_size, void* d_ws, size_t ws_size,
                              hipStream_t stream) {
    const float* x_ball = (const float*)d_in[0];
    const float* x_player = (const float*)d_in[1];
    const float* x_context = (const float*)d_in[2];
    const int* em = (const int*)d_in[3];
    const int* ep = (const int*)d_in[4];
    const int* ei = (const int*)d_in[5];
    const float* ea_p = (const float*)d_in[6];
    const float* g_Wl = (const float*)d_in[7];
    const float* g_Wr = (const float*)d_in[8];
    const float* g_att = (const float*)d_in[9];
    const float* g_b = (const float*)d_in[10];
    const float* t_Wq = (const float*)d_in[11];
    const float* t_bq = (const float*)d_in[12];
    const float* t_Wk = (const float*)d_in[13];
    const float* t_bk = (const float*)d_in[14];
    const float* t_Wv = (const float*)d_in[15];
    const float* t_bv = (const float*)d_in[16];
    const float* t_We = (const float*)d_in[17];
    const float* t_Wskip = (const float*)d_in[18];
    const float* t_bskip = (const float*)d_in[19];
    const float* s_Wl = (const float*)d_in[20];
    const float* s_bl = (const float*)d_in[21];
    const float* s_Wr = (const float*)d_in[22];
    const float* ln_ball_g = (const float*)d_in[23];
    const float* ln_ball_b = (const float*)d_in[24];
    const float* ln_ctx_g = (const float*)d_in[25];
    const float* ln_ctx_b = (const float*)d_in[26];
    float* out = (float*)d_out;

    // ---- workspace (~87 MB) ----
    float* ws = (float*)d_ws;
    size_t o = 0;
    float* summ = ws + o;           o += (size_t)NC * 128;
    int* counts = (int*)(ws + o);   o += SEG_TOT;
    int* offsets = (int*)(ws + o);  o += SEG_TOT;
    int* cursors = (int*)(ws + o);  o += SEG_TOT;
    int* partials = (int*)(ws + o); o += 128;
    if (o & 1) o++;                               // 8B align for int2 pool
    int2* pool = (int2*)(ws + o);   o += (size_t)POOL_N * 2;
    ushort* Wt = (ushort*)(ws + o); o += (6 * 16384) / 2;
    u32* xlP = (u32*)(ws + o);      o += (size_t)NP * 64;
    u32* xrP = (u32*)(ws + o);      o += (size_t)NB * 64;
    u32* qP = (u32*)(ws + o);       o += (size_t)NB * 64;
    u32* skipP = (u32*)(ws + o);    o += (size_t)NB * 64;
    if (o & 1) o++;                               // 8B align for uint2 kv loads
    u32* kvP = (u32*)(ws + o);      o += (size_t)NB * 128;

    dim3 blk(256);
    // ---- CSR build (+ 6-weight transpose folded into hist) ----
    hipMemsetAsync(counts, 0, SEG_TOT * sizeof(int), stream);
    hist_wt_kernel<<<(POOL_N + 255) / 256, blk, 0, stream>>>(em, ep, ei, counts,
                                                             g_Wr, t_Wq, t_Wk, t_Wv, t_Wskip, g_Wl, Wt);
    scan1_kernel<<<NPART, blk, 0, stream>>>(counts, offsets, partials);
    scan23_kernel<<<NPART, blk, 0, stream>>>(offsets, partials, cursors);
    fill_all_kernel<<<(POOL_N + 255) / 256, blk, 0, stream>>>(em, ep, ei, ea_p, cursors, pool);

    // ---- dense projections (ball 5-weight + player 1-weight in one launch) ----
    gemm6_mfma_kernel<<<BALL_BLKS + PLYR_BLKS, blk, 0, stream>>>(
        x_ball, x_player, Wt, t_bq, t_bk, t_bv, t_bskip, xrP, qP, kvP, skipP, xlP);

    // ---- fused ball pipeline ----
    ball_fused_kernel<<<(NB + 3) / 4, blk, 0, stream>>>(
        xlP, xrP, qP, kvP, skipP, x_ball, g_att, g_b, t_We,
        offsets, counts, pool, ln_ball_g, ln_ball_b, out);

    // ---- SAGE -> ctx ----
    sage_gather4_kernel<<<NC, blk, 0, stream>>>(x_ball, offsets, counts, pool, summ);
    ctx_fused_kernel<<<(NC + 15) / 16, blk, 0, stream>>>(x_context, summ, s_Wr, s_Wl, s_bl,
                                                         ln_ctx_g, ln_ctx_b, out + (size_t)NB * 128);
    copy_player_kernel<<<(NP * 128 + 255) / 256, blk, 0, stream>>>(x_player,
                                                                   out + (size_t)(NB + NC) * 128);
}

// Round 10
// 332.343 us; speedup vs baseline: 1.4896x; 1.0646x over previous
//
#include <hip/hip_runtime.h>
#include <hip/hip_bf16.h>

#define NB 60000
#define NP 2000
#define NC 4000
#define EM_N 150000
#define EP_N 300000
#define EI_N 150000
#define POOL_N (EM_N + EP_N + EI_N)
#define SEG_TOT (NB + NB + NC)
#define SCAN_BLK 1024
#define NPART ((SEG_TOT + SCAN_BLK - 1) / SCAN_BLK)   // 122
#define BALL_BLKS ((NB + 127) / 128)                  // 469
#define PLYR_BLKS ((NP + 127) / 128)                  // 16
#define GEMM_BLKS (BALL_BLKS + PLYR_BLKS)             // 485
#define FILL_BLKS ((POOL_N + 255) / 256)              // 2344
#define BBALL ((NB + 3) / 4)                          // 15000
#define COPY_BLKS ((NP * 128 + 255) / 256)            // 1000

typedef __hip_bfloat16 bf16;
typedef unsigned int u32;
typedef __attribute__((ext_vector_type(8))) short s8v;
typedef __attribute__((ext_vector_type(4))) float f4v;

__device__ __forceinline__ short f2bs(float f) {
    bf16 h = __float2bfloat16(f);
    return __builtin_bit_cast(short, h);
}
__device__ __forceinline__ float bsToF(short s) {
    return __builtin_bit_cast(float, ((unsigned)(unsigned short)s) << 16);
}
__device__ __forceinline__ float loF(u32 v) { return bsToF((short)(v & 0xffff)); }
__device__ __forceinline__ float hiF(u32 v) { return bsToF((short)(v >> 16)); }
__device__ __forceinline__ u32 packbf(float a, float b) {
    return (u32)(unsigned short)f2bs(a) | ((u32)(unsigned short)f2bs(b) << 16);
}

// ---------------- hist + 6-weight transpose ----------------
__global__ void hist_wt_kernel(const int* __restrict__ em, const int* __restrict__ ep,
                               const int* __restrict__ ei, int* __restrict__ counts,
                               const float* __restrict__ W0, const float* __restrict__ W1,
                               const float* __restrict__ W2, const float* __restrict__ W3,
                               const float* __restrict__ W4, const float* __restrict__ W5,
                               ushort* __restrict__ Wt) {
    int t = blockIdx.x * 256 + threadIdx.x;
    if (t < 6 * 16384) {
        int w = t >> 14, r = t & 16383, k = r >> 7, n = r & 127;
        const float* W = (w == 0) ? W0 : (w == 1) ? W1 : (w == 2) ? W2 : (w == 3) ? W3
                       : (w == 4) ? W4 : W5;
        int sc = (n >> 5) * 32 + ((n & 1) << 4) + ((n & 31) >> 1);
        Wt[w * 16384 + sc * 128 + k] = (unsigned short)f2bs(W[k * 128 + n]);
    }
    if (t < EM_N) atomicAdd(&counts[em[EM_N + t]], 1);
    else if (t < EM_N + EP_N) atomicAdd(&counts[NB + ep[EP_N + (t - EM_N)]], 1);
    else if (t < POOL_N) atomicAdd(&counts[2 * NB + ei[EI_N + (t - EM_N - EP_N)]], 1);
}

// ---------------- fused scan: block-local scan + atomic base ----------------
// Segment ranges are contiguous & unique; base assignment order is nondeterministic,
// which only permutes segment placement in the pool (math unaffected).
__global__ void scan_fused_kernel(const int* __restrict__ counts, int* __restrict__ offsets,
                                  int* __restrict__ cursors, int* __restrict__ gbase) {
    __shared__ int sd[256];
    __shared__ int sbase;
    int b = blockIdx.x, tid = threadIdx.x;
    int base = b * SCAN_BLK + tid * 4;
    int v[4]; int ts = 0;
#pragma unroll
    for (int j = 0; j < 4; j++) { int idx = base + j; v[j] = (idx < SEG_TOT) ? counts[idx] : 0; ts += v[j]; }
    sd[tid] = ts;
    for (int off = 1; off < 256; off <<= 1) {
        __syncthreads(); int t = (tid >= off) ? sd[tid - off] : 0;
        __syncthreads(); sd[tid] += t;
    }
    __syncthreads();
    if (tid == 255) sbase = atomicAdd(gbase, sd[255]);
    __syncthreads();
    int run = sd[tid] - ts + sbase;
#pragma unroll
    for (int j = 0; j < 4; j++) {
        int idx = base + j;
        if (idx < SEG_TOT) { offsets[idx] = run; cursors[idx] = run; }
        run += v[j];
    }
}

// ---------------- merged: MFMA 6-matrix GEMM blocks + pool-fill blocks ----------------
__global__ __launch_bounds__(256) void gemm6_fill_kernel(
    const float* __restrict__ Aball, const float* __restrict__ Aplyr,
    const ushort* __restrict__ Wt,
    const float* __restrict__ bq, const float* __restrict__ bk,
    const float* __restrict__ bv_, const float* __restrict__ bskip,
    u32* __restrict__ xrP, u32* __restrict__ qP, u32* __restrict__ kvP,
    u32* __restrict__ skipP, u32* __restrict__ xlP,
    const int* __restrict__ em, const int* __restrict__ ep, const int* __restrict__ ei,
    const float* __restrict__ ea_p, int* __restrict__ cursors, int2* __restrict__ pool) {
    if (blockIdx.x >= GEMM_BLKS) {
        // ---- fill path ----
        int t = (blockIdx.x - GEMM_BLKS) * 256 + threadIdx.x;
        int seg, s; float ea = 0.f;
        if (t < EM_N) { s = em[t]; seg = em[EM_N + t]; }
        else if (t < EM_N + EP_N) { int e = t - EM_N; s = ep[e]; seg = NB + ep[EP_N + e]; ea = ea_p[e]; }
        else if (t < POOL_N) { int e = t - EM_N - EP_N; s = ei[e]; seg = 2 * NB + ei[EI_N + e]; }
        else return;
        int pos = atomicAdd(&cursors[seg], 1);
        pool[pos] = make_int2(s, __float_as_int(ea));
        return;
    }
    // ---- GEMM path ----
    const int lane = threadIdx.x & 63;
    const int wv = threadIdx.x >> 6;
    const int quad = lane >> 4, l16 = lane & 15;
    const bool plyr = (blockIdx.x >= BALL_BLKS);
    const int M = plyr ? NP : NB;
    const float* A = plyr ? Aplyr : Aball;
    const int mbase = (plyr ? (blockIdx.x - BALL_BLKS) : blockIdx.x) * 128 + wv * 32;

    s8v a[2][4];
#pragma unroll
    for (int mt = 0; mt < 2; mt++) {
        int row = mbase + mt * 16 + l16;
        if (row >= M) row = M - 1;
        const float* ap = A + (size_t)row * 128 + quad * 8;
#pragma unroll
        for (int kt = 0; kt < 4; kt++) {
            const float4* p = (const float4*)(ap + kt * 32);
            float4 u = p[0], v = p[1];
            s8v f;
            f[0] = f2bs(u.x); f[1] = f2bs(u.y); f[2] = f2bs(u.z); f[3] = f2bs(u.w);
            f[4] = f2bs(v.x); f[5] = f2bs(v.y); f[6] = f2bs(v.z); f[7] = f2bs(v.w);
            a[mt][kt] = f;
        }
    }

    const int wbeg = plyr ? 5 : 0, wend = plyr ? 6 : 5;
    for (int w = wbeg; w < wend; w++) {
        const ushort* wt = Wt + w * 16384;
        u32* op; const float* bp; int stride, obase;
        if (w == 0)      { op = xrP;   bp = nullptr; stride = 64;  obase = 0; }
        else if (w == 1) { op = qP;    bp = bq;      stride = 64;  obase = 0; }
        else if (w == 2) { op = kvP;   bp = bk;      stride = 128; obase = 0; }
        else if (w == 3) { op = kvP;   bp = bv_;     stride = 128; obase = 1; }
        else if (w == 4) { op = skipP; bp = bskip;   stride = 64;  obase = 0; }
        else             { op = xlP;   bp = nullptr; stride = 64;  obase = 0; }
        const int kvmul = (stride == 128) ? 2 : 1;
#pragma unroll
        for (int t = 0; t < 4; t++) {
            s8v blo[4], bhi[4];
#pragma unroll
            for (int kt = 0; kt < 4; kt++) {
                blo[kt] = *(const s8v*)(wt + (t * 32 + l16) * 128 + kt * 32 + quad * 8);
                bhi[kt] = *(const s8v*)(wt + (t * 32 + 16 + l16) * 128 + kt * 32 + quad * 8);
            }
            float bvlo = 0.f, bvhi = 0.f;
            if (bp) { float2 b2 = ((const float2*)bp)[t * 16 + l16]; bvlo = b2.x; bvhi = b2.y; }
#pragma unroll
            for (int mt = 0; mt < 2; mt++) {
                f4v alo = {0.f, 0.f, 0.f, 0.f}, ahi = {0.f, 0.f, 0.f, 0.f};
#pragma unroll
                for (int kt = 0; kt < 4; kt++) {
                    alo = __builtin_amdgcn_mfma_f32_16x16x32_bf16(a[mt][kt], blo[kt], alo, 0, 0, 0);
                    ahi = __builtin_amdgcn_mfma_f32_16x16x32_bf16(a[mt][kt], bhi[kt], ahi, 0, 0, 0);
                }
#pragma unroll
                for (int r = 0; r < 4; r++) {
                    int row = mbase + mt * 16 + quad * 4 + r;
                    if (row < M)
                        op[(size_t)row * stride + (t * 16 + l16) * kvmul + obase]
                            = packbf(alo[r] + bvlo, ahi[r] + bvhi);
                }
            }
        }
    }
}

// ---------------- merged: ball (GAT+TR+skip+LN) | sage gather | player copy ----------------
__global__ __launch_bounds__(256) void ball_sage_copy_kernel(
    const u32* __restrict__ xlP, const u32* __restrict__ xrP, const u32* __restrict__ qP,
    const u32* __restrict__ kvP, const u32* __restrict__ skipP,
    const float* __restrict__ x_ball, const float* __restrict__ x_player,
    const float* __restrict__ g_att, const float* __restrict__ g_b,
    const float* __restrict__ We,
    const int* __restrict__ offsets, const int* __restrict__ counts,
    const int2* __restrict__ pool,
    const float* __restrict__ ln_g, const float* __restrict__ ln_b,
    float* __restrict__ summ, float* __restrict__ out) {
    __shared__ float part[4][128];
    const int wv = threadIdx.x >> 6, l = threadIdx.x & 63;

    if (blockIdx.x >= BBALL + NC) {
        // ---- player passthrough ----
        int t = (blockIdx.x - BBALL - NC) * 256 + threadIdx.x;
        if (t < NP * 128) out[(size_t)(NB + NC) * 128 + t] = x_player[t];
        return;
    }
    if (blockIdx.x >= BBALL) {
        // ---- SAGE gather (4-way edge split per ctx node) ----
        int c = blockIdx.x - BBALL;
        int beg = offsets[2 * NB + c], cnt = counts[2 * NB + c];
        float s0 = 0.f, s1 = 0.f;
        for (int j = wv; j < cnt; j += 4) {
            int s = pool[beg + j].x;
            float2 xv = ((const float2*)x_ball)[(size_t)s * 64 + l];
            s0 += xv.x; s1 += xv.y;
        }
        part[wv][l * 2] = s0; part[wv][l * 2 + 1] = s1;
        __syncthreads();
        if (wv == 0) {
            float m = fmaxf((float)cnt, 1.f);
            size_t rowC = (size_t)c * 128;
            summ[rowC + l * 2] = (part[0][l * 2] + part[1][l * 2] + part[2][l * 2] + part[3][l * 2]) / m;
            summ[rowC + l * 2 + 1] =
                (part[0][l * 2 + 1] + part[1][l * 2 + 1] + part[2][l * 2 + 1] + part[3][l * 2 + 1]) / m;
        }
        return;
    }

    // ---- ball path: one wave per node, pairing (2l,2l+1), head = l>>4 ----
    const int d = blockIdx.x * 4 + wv;
    if (d >= NB) return;
    const size_t rowD = (size_t)d * 64;

    // ======== GATv2 (player -> ball), 4-edge pipeline ========
    float2 att = ((const float2*)g_att)[l];
    u32 xr2 = xrP[rowD + l];
    float xr0 = loF(xr2), xr1 = hiF(xr2);
    int beg = offsets[d], cnt = counts[d];
    float n0 = 0.f, n1 = 0.f, deg = 0.f;
    int j = 0;
    for (; j + 3 < cnt; j += 4) {
        int s0 = pool[beg + j].x, s1 = pool[beg + j + 1].x;
        int s2 = pool[beg + j + 2].x, s3 = pool[beg + j + 3].x;
        u32 xv0 = xlP[(size_t)s0 * 64 + l], xv1 = xlP[(size_t)s1 * 64 + l];
        u32 xv2 = xlP[(size_t)s2 * 64 + l], xv3 = xlP[(size_t)s3 * 64 + l];
        float p[4], xa[4], xb[4];
        u32 xv[4] = {xv0, xv1, xv2, xv3};
#pragma unroll
        for (int i = 0; i < 4; i++) {
            xa[i] = loF(xv[i]); xb[i] = hiF(xv[i]);
            float u0 = xa[i] + xr0; u0 = u0 > 0.f ? u0 : 0.2f * u0;
            float u1 = xb[i] + xr1; u1 = u1 > 0.f ? u1 : 0.2f * u1;
            p[i] = u0 * att.x + u1 * att.y;
        }
#pragma unroll
        for (int m = 1; m <= 8; m <<= 1) {
#pragma unroll
            for (int i = 0; i < 4; i++) p[i] += __shfl_xor(p[i], m);
        }
#pragma unroll
        for (int i = 0; i < 4; i++) {
            p[i] = __expf(p[i]);
            n0 += p[i] * xa[i]; n1 += p[i] * xb[i]; deg += p[i];
        }
    }
    for (; j < cnt; j++) {
        int s = pool[beg + j].x;
        u32 xv = xlP[(size_t)s * 64 + l];
        float x0 = loF(xv), x1 = hiF(xv);
        float u0 = x0 + xr0; u0 = u0 > 0.f ? u0 : 0.2f * u0;
        float u1 = x1 + xr1; u1 = u1 > 0.f ? u1 : 0.2f * u1;
        float p = u0 * att.x + u1 * att.y;
#pragma unroll
        for (int m = 1; m <= 8; m <<= 1) p += __shfl_xor(p, m);
        p = __expf(p);
        n0 += p * x0; n1 += p * x1; deg += p;
    }
    float gat0 = n0 / (deg + 1e-16f), gat1 = n1 / (deg + 1e-16f);

    // ======== TransformerConv (ball -> ball), 4-edge pipeline ========
    u32 q2 = qP[rowD + l];
    float q0 = loF(q2), q1 = hiF(q2);
    float2 we = ((const float2*)We)[l];
    float dw = q0 * we.x + q1 * we.y;
#pragma unroll
    for (int m = 1; m <= 8; m <<= 1) dw += __shfl_xor(dw, m);
    beg = offsets[NB + d]; cnt = counts[NB + d];
    float sv0 = 0.f, sv1 = 0.f, spe = 0.f, det = 0.f;
    const uint2* kv2p = (const uint2*)kvP;
    j = 0;
    for (; j + 3 < cnt; j += 4) {
        int2 pr[4] = {pool[beg + j], pool[beg + j + 1], pool[beg + j + 2], pool[beg + j + 3]};
        uint2 kv[4];
#pragma unroll
        for (int i = 0; i < 4; i++) kv[i] = kv2p[(size_t)pr[i].x * 64 + l];
        float p[4], ea[4];
#pragma unroll
        for (int i = 0; i < 4; i++) {
            ea[i] = __int_as_float(pr[i].y);
            p[i] = q0 * loF(kv[i].x) + q1 * hiF(kv[i].x);
        }
#pragma unroll
        for (int m = 1; m <= 8; m <<= 1) {
#pragma unroll
            for (int i = 0; i < 4; i++) p[i] += __shfl_xor(p[i], m);
        }
#pragma unroll
        for (int i = 0; i < 4; i++) {
            p[i] = __expf((p[i] + ea[i] * dw) * 0.17677669529663687f);
            sv0 += p[i] * loF(kv[i].y); sv1 += p[i] * hiF(kv[i].y);
            spe += p[i] * ea[i]; det += p[i];
        }
    }
    for (; j < cnt; j++) {
        int2 pr = pool[beg + j];
        float ea = __int_as_float(pr.y);
        uint2 kv = kv2p[(size_t)pr.x * 64 + l];
        float p = q0 * loF(kv.x) + q1 * hiF(kv.x);
#pragma unroll
        for (int m = 1; m <= 8; m <<= 1) p += __shfl_xor(p, m);
        p = __expf((p + ea * dw) * 0.17677669529663687f);
        sv0 += p * loF(kv.y); sv1 += p * hiF(kv.y);
        spe += p * ea; det += p;
    }
    float tr0 = (sv0 + spe * we.x) / (det + 1e-16f);
    float tr1 = (sv1 + spe * we.y) / (det + 1e-16f);

    // ======== skip + residual + LayerNorm ========
    u32 sk = skipP[rowD + l];
    float2 xb2 = ((const float2*)x_ball)[rowD + l];
    float2 gb2 = ((const float2*)g_b)[l];
    float val0 = loF(sk) + gat0 + tr0 + xb2.x + gb2.x;
    float val1 = hiF(sk) + gat1 + tr1 + xb2.y + gb2.y;
    float s = val0 + val1;
#pragma unroll
    for (int m = 1; m <= 32; m <<= 1) s += __shfl_xor(s, m);
    float mu = s * (1.f / 128.f);
    float d0 = val0 - mu, d1 = val1 - mu;
    float qv = d0 * d0 + d1 * d1;
#pragma unroll
    for (int m = 1; m <= 32; m <<= 1) qv += __shfl_xor(qv, m);
    float inv = rsqrtf(qv * (1.f / 128.f) + 1e-5f);
    float2 g2 = ((const float2*)ln_g)[l];
    float2 b2 = ((const float2*)ln_b)[l];
    ((float2*)out)[rowD + l] = make_float2(d0 * inv * g2.x + b2.x, d1 * inv * g2.y + b2.y);
}

// ---------------- fused ctx: xc@Wr + summ@Wl + bl + residual + LN ----------------
__global__ void ctx_fused_kernel(const float* __restrict__ xc, const float* __restrict__ summ,
                                 const float* __restrict__ Wr, const float* __restrict__ Wl,
                                 const float* __restrict__ bl,
                                 const float* __restrict__ g, const float* __restrict__ b,
                                 float* __restrict__ out) {
    __shared__ float A0[16 * 128];
    __shared__ float A1[16 * 128];
    __shared__ float CB[16 * 128];
    const int tid = threadIdx.x;
    const int row0 = blockIdx.x * 16;
    for (int i = tid; i < 16 * 128; i += 256) {
        int r = row0 + (i >> 7);
        A0[i] = (r < NC) ? xc[(size_t)r * 128 + (i & 127)] : 0.f;
        A1[i] = (r < NC) ? summ[(size_t)r * 128 + (i & 127)] : 0.f;
    }
    __syncthreads();
    const int col = tid & 127, rg = tid >> 7;
    float acc[8];
#pragma unroll
    for (int i = 0; i < 8; i++) acc[i] = 0.f;
    for (int k = 0; k < 128; k++) {
        float w0 = Wr[k * 128 + col], w1 = Wl[k * 128 + col];
#pragma unroll
        for (int i = 0; i < 8; i++)
            acc[i] += A0[(rg * 8 + i) * 128 + k] * w0 + A1[(rg * 8 + i) * 128 + k] * w1;
    }
    float bv = bl[col];
#pragma unroll
    for (int i = 0; i < 8; i++)
        CB[(rg * 8 + i) * 128 + col] = acc[i] + bv + A0[(rg * 8 + i) * 128 + col];
    __syncthreads();
    const int wv = tid >> 6, l = tid & 63;
    for (int r = 0; r < 4; r++) {
        int lr = wv * 4 + r, row = row0 + lr;
        if (row >= NC) break;
        float v0 = CB[lr * 128 + l], v1 = CB[lr * 128 + l + 64];
        float s = v0 + v1;
#pragma unroll
        for (int m = 1; m <= 32; m <<= 1) s += __shfl_xor(s, m);
        float mu = s * (1.f / 128.f);
        float d0 = v0 - mu, d1 = v1 - mu;
        float qv = d0 * d0 + d1 * d1;
#pragma unroll
        for (int m = 1; m <= 32; m <<= 1) qv += __shfl_xor(qv, m);
        float inv = rsqrtf(qv * (1.f / 128.f) + 1e-5f);
        out[(size_t)row * 128 + l] = d0 * inv * g[l] + b[l];
        out[(size_t)row * 128 + l + 64] = d1 * inv * g[l + 64] + b[l + 64];
    }
}

extern "C" void kernel_launch(void* const* d_in, const int* in_sizes, int n_in,
                              void* d_out, int out_size, void* d_ws, size_t ws_size,
                              hipStream_t stream) {
    const float* x_ball = (const float*)d_in[0];
    const float* x_player = (const float*)d_in[1];
    const float* x_context = (const float*)d_in[2];
    const int* em = (const int*)d_in[3];
    const int* ep = (const int*)d_in[4];
    const int* ei = (const int*)d_in[5];
    const float* ea_p = (const float*)d_in[6];
    const float* g_Wl = (const float*)d_in[7];
    const float* g_Wr = (const float*)d_in[8];
    const float* g_att = (const float*)d_in[9];
    const float* g_b = (const float*)d_in[10];
    const float* t_Wq = (const float*)d_in[11];
    const float* t_bq = (const float*)d_in[12];
    const float* t_Wk = (const float*)d_in[13];
    const float* t_bk = (const float*)d_in[14];
    const float* t_Wv = (const float*)d_in[15];
    const float* t_bv = (const float*)d_in[16];
    const float* t_We = (const float*)d_in[17];
    const float* t_Wskip = (const float*)d_in[18];
    const float* t_bskip = (const float*)d_in[19];
    const float* s_Wl = (const float*)d_in[20];
    const float* s_bl = (const float*)d_in[21];
    const float* s_Wr = (const float*)d_in[22];
    const float* ln_ball_g = (const float*)d_in[23];
    const float* ln_ball_b = (const float*)d_in[24];
    const float* ln_ctx_g = (const float*)d_in[25];
    const float* ln_ctx_b = (const float*)d_in[26];
    float* out = (float*)d_out;

    // ---- workspace (~87 MB) ----
    float* ws = (float*)d_ws;
    size_t o = 0;
    float* summ = ws + o;           o += (size_t)NC * 128;
    int* counts = (int*)(ws + o);   o += SEG_TOT;
    int* gbase = (int*)(ws + o);    o += 1;     // zeroed together with counts
    int* offsets = (int*)(ws + o);  o += SEG_TOT;
    int* cursors = (int*)(ws + o);  o += SEG_TOT;
    if (o & 1) o++;
    int2* pool = (int2*)(ws + o);   o += (size_t)POOL_N * 2;
    ushort* Wt = (ushort*)(ws + o); o += (6 * 16384) / 2;
    u32* xlP = (u32*)(ws + o);      o += (size_t)NP * 64;
    u32* xrP = (u32*)(ws + o);      o += (size_t)NB * 64;
    u32* qP = (u32*)(ws + o);       o += (size_t)NB * 64;
    u32* skipP = (u32*)(ws + o);    o += (size_t)NB * 64;
    if (o & 1) o++;
    u32* kvP = (u32*)(ws + o);      o += (size_t)NB * 128;

    dim3 blk(256);
    hipMemsetAsync(counts, 0, (SEG_TOT + 1) * sizeof(int), stream);
    hist_wt_kernel<<<(POOL_N + 255) / 256, blk, 0, stream>>>(em, ep, ei, counts,
                                                             g_Wr, t_Wq, t_Wk, t_Wv, t_Wskip, g_Wl, Wt);
    scan_fused_kernel<<<NPART, blk, 0, stream>>>(counts, offsets, cursors, gbase);
    gemm6_fill_kernel<<<GEMM_BLKS + FILL_BLKS, blk, 0, stream>>>(
        x_ball, x_player, Wt, t_bq, t_bk, t_bv, t_bskip, xrP, qP, kvP, skipP, xlP,
        em, ep, ei, ea_p, cursors, pool);
    ball_sage_copy_kernel<<<BBALL + NC + COPY_BLKS, blk, 0, stream>>>(
        xlP, xrP, qP, kvP, skipP, x_ball, x_player, g_att, g_b, t_We,
        offsets, counts, pool, ln_ball_g, ln_ball_b, summ, out);
    ctx_fused_kernel<<<(NC + 15) / 16, blk, 0, stream>>>(x_context, summ, s_Wr, s_Wl, s_bl,
                                                         ln_ctx_g, ln_ctx_b, out + (size_t)NB * 128);
}